// Round 6
// baseline (121.446 us; speedup 1.0000x reference)
//
#include <hip/hip_runtime.h>

// Problem constants: B=1024, F=33, D=128, A=128, P=F*(F-1)/2=528
#define FN 33
#define DN 128
#define AN 128
#define PN 528
#define MTN 33     // P / 16 M-tiles, exact
#define XS 136     // fp16 row stride for xh in LDS (272 B, 16B-aligned, non-pow2)
#define AS 36      // u32 row stride for attn_h2 (144 B, 16B-aligned)

typedef __attribute__((ext_vector_type(8))) _Float16 half8;
typedef __attribute__((ext_vector_type(2))) _Float16 h2;
typedef __attribute__((ext_vector_type(4))) float f32x4;
typedef __attribute__((ext_vector_type(2))) float f32x2;
typedef __attribute__((ext_vector_type(4))) unsigned int u32x4;

__device__ __forceinline__ unsigned int pkrtz(float a, float b) {
  return __builtin_bit_cast(unsigned int, __builtin_amdgcn_cvt_pkrtz(a, b));
}
__device__ __forceinline__ h2 ash2(unsigned int u) { return __builtin_bit_cast(h2, u); }

// sum over the 16-lane DPP row via row_ror rotations (VALU pipe, no LDS)
__device__ __forceinline__ float row_sum16(float v) {
  v += __builtin_bit_cast(float, __builtin_amdgcn_update_dpp(0, __builtin_bit_cast(int, v), 0x128, 0xF, 0xF, false));
  v += __builtin_bit_cast(float, __builtin_amdgcn_update_dpp(0, __builtin_bit_cast(int, v), 0x124, 0xF, 0xF, false));
  v += __builtin_bit_cast(float, __builtin_amdgcn_update_dpp(0, __builtin_bit_cast(int, v), 0x122, 0xF, 0xF, false));
  v += __builtin_bit_cast(float, __builtin_amdgcn_update_dpp(0, __builtin_bit_cast(int, v), 0x121, 0xF, 0xF, false));
  return v;
}

__global__ __launch_bounds__(256, 2)
void afm_kernel(const float* __restrict__ gnn, const float* __restrict__ xg,
                const float* __restrict__ Wg,  const float* __restrict__ bg,
                float* __restrict__ out)
{
  __shared__ __align__(16) _Float16 xh[FN * XS];        // x[row] fp16, [i][d]   (8976 B)
  __shared__ __align__(16) unsigned int attn_h2[FN * AS]; // exp, dup f16x2      (4752 B)
  __shared__ __align__(16) float scores_s[PN];          // (2112 B)
  __shared__ __align__(16) float part[512];             // epilogue partials per wave (2048 B)
  __shared__ unsigned short rowcol[PN];                 // i | (j<<8)            (1056 B)
  __shared__ float red[8];

  const int tid  = threadIdx.x;
  const int wave = tid >> 6;
  const int lane = tid & 63;
  const int q    = lane >> 4;   // quad 0..3
  const int u    = lane & 15;

  // ---------------- once per block: rowcol + B-fragments (W resident, fp16, AGPR) ----------------
  for (int p = tid; p < PN; p += 256) {
    int i = 0, rem = p;
    while (rem >= FN - 1 - i) { rem -= FN - 1 - i; i++; }
    rowcol[p] = (unsigned short)(i | ((i + 1 + rem) << 8));
  }
  // Bf[n][kk]: lane holds W[a = n*16+u][k = kk*32 + q*8 .. +7]
  half8 Bf[8][4];
  #pragma unroll
  for (int n = 0; n < 8; n++) {
    const float* wrow = Wg + (size_t)(n * 16 + u) * DN + q * 8;
    #pragma unroll
    for (int kk = 0; kk < 4; kk++) {
      f32x4 w0 = *(const f32x4*)(wrow + kk * 32);
      f32x4 w1 = *(const f32x4*)(wrow + kk * 32 + 4);
      union { half8 h; unsigned int w[4]; } t;
      t.w[0] = pkrtz(w0.x, w0.y);
      t.w[1] = pkrtz(w0.z, w0.w);
      t.w[2] = pkrtz(w1.x, w1.y);
      t.w[3] = pkrtz(w1.z, w1.w);
      Bf[n][kk] = t.h;
      asm volatile("" : "+v"(Bf[n][kk]));   // pin: forbid remat (lands in AGPRs)
    }
  }
  float barr[8];
  #pragma unroll
  for (int n = 0; n < 8; n++) { barr[n] = bg[n * 16 + u]; asm volatile("" : "+v"(barr[n])); }

  // ---------------- persistent loop: 2 batch rows per block ----------------
  #pragma unroll 1
  for (int r2 = 0; r2 < 2; r2++) {
    const int b = blockIdx.x * 2 + r2;

    float garr[8];
    #pragma unroll
    for (int n = 0; n < 8; n++) { garr[n] = gnn[(size_t)b * AN + n * 16 + u]; asm volatile("" : "+v"(garr[n])); }

    // stage x[b] -> fp16 LDS; zero attn_h2
    const f32x4* xg4 = (const f32x4*)(xg + (size_t)b * FN * DN);
    for (int idx = tid; idx < (FN * DN) / 4; idx += 256) {   // 1056 float4
      f32x4 v = xg4[idx];
      int i  = idx >> 5;
      int d0 = (idx & 31) << 2;
      *(uint2*)&xh[i * XS + d0] = make_uint2(pkrtz(v.x, v.y), pkrtz(v.z, v.w));
    }
    for (int idx = tid; idx < FN * AS; idx += 256) attn_h2[idx] = 0u;
    __syncthreads();                                         // (A)

    // ---- fm matmul + score: fp16 MFMA, m-split over waves, software-pipelined ----
    {
      int mt = wave;
      unsigned int rc = rowcol[mt * 16 + u];
      int r = rc & 255, c = rc >> 8;
      half8 xr[4], xc[4];
      #pragma unroll
      for (int kk = 0; kk < 4; kk++) {
        xr[kk] = *(const half8*)&xh[r * XS + kk * 32 + q * 8];
        xc[kk] = *(const half8*)&xh[c * XS + kk * 32 + q * 8];
      }
      for (;;) {
        half8 Af[4];
        #pragma unroll
        for (int kk = 0; kk < 4; kk++) Af[kk] = xr[kk] * xc[kk];   // v_pk_mul_f16

        const int nmt = mt + 4;
        if (nmt < MTN) {                                    // prefetch next tile's A rows
          rc = rowcol[nmt * 16 + u];
          r = rc & 255; c = rc >> 8;
          #pragma unroll
          for (int kk = 0; kk < 4; kk++) {
            xr[kk] = *(const half8*)&xh[r * XS + kk * 32 + q * 8];
            xc[kk] = *(const half8*)&xh[c * XS + kk * 32 + q * 8];
          }
        }

        float sc[4] = {0.f, 0.f, 0.f, 0.f};
        #pragma unroll
        for (int g = 0; g < 2; g++) {                       // n in groups of 4 (acc = 16 VGPR)
          f32x4 acc[4];
          #pragma unroll
          for (int nn = 0; nn < 4; nn++) {
            float bv = barr[g * 4 + nn];                    // bias folded into acc init
            acc[nn] = (f32x4){bv, bv, bv, bv};
          }
          #pragma unroll
          for (int kk = 0; kk < 4; kk++)
            #pragma unroll
            for (int nn = 0; nn < 4; nn++)
              acc[nn] = __builtin_amdgcn_mfma_f32_16x16x32_f16(Af[kk], Bf[g * 4 + nn][kk], acc[nn], 0, 0, 0);
          #pragma unroll
          for (int nn = 0; nn < 4; nn++)
            #pragma unroll
            for (int rr = 0; rr < 4; rr++) {
              float fmv = fmaxf(acc[nn][rr], 0.f);          // relu (bias already in)
              sc[rr] = fmaf(fmv, garr[g * 4 + nn], sc[rr]);
            }
        }
        #pragma unroll
        for (int rr = 0; rr < 4; rr++) sc[rr] = row_sum16(sc[rr]);
        if (u == 0)
          *(f32x4*)&scores_s[mt * 16 + q * 4] = (f32x4){sc[0], sc[1], sc[2], sc[3]};

        if (nmt >= MTN) break;
        mt = nmt;
      }
    }
    __syncthreads();                                         // (B)

    // ---------------- softmax over 528 scores ----------------
    float s0 = scores_s[tid];
    float s1 = scores_s[tid + 256];
    float s2 = (tid < 16) ? scores_s[tid + 512] : -3.4e38f;
    float m = fmaxf(fmaxf(s0, s1), s2);
    #pragma unroll
    for (int off = 32; off >= 1; off >>= 1) m = fmaxf(m, __shfl_xor(m, off, 64));
    if (lane == 0) red[wave] = m;
    __syncthreads();                                         // (C)
    const float smax = fmaxf(fmaxf(red[0], red[1]), fmaxf(red[2], red[3]));

    float e0 = __expf(s0 - smax);
    float e1 = __expf(s1 - smax);
    float e2 = (tid < 16) ? __expf(s2 - smax) : 0.f;
    {
      unsigned int rc = rowcol[tid];
      attn_h2[(rc & 255) * AS + ((rc >> 8) - (rc & 255) - 1)] = pkrtz(e0, e0);
      rc = rowcol[tid + 256];
      attn_h2[(rc & 255) * AS + ((rc >> 8) - (rc & 255) - 1)] = pkrtz(e1, e1);
      if (tid < 16) {
        rc = rowcol[tid + 512];
        attn_h2[(rc & 255) * AS + ((rc >> 8) - (rc & 255) - 1)] = pkrtz(e2, e2);
      }
    }
    float lsum = e0 + e1 + e2;
    #pragma unroll
    for (int off = 32; off >= 1; off >>= 1) lsum += __shfl_xor(lsum, off, 64);
    if (lane == 0) red[4 + wave] = lsum;
    __syncthreads();                                         // (D)
    const float Z = red[4] + red[5] + red[6] + red[7];

    // ---- epilogue: out_d = sum_i x_i[d] * (sum_j attn_ij x_j[d]); lane owns d=2l,2l+1;
    //      wave owns rows i == wave (mod 4) (balanced, no duplicate attn reads) ----
    {
      unsigned int xp[36];                                   // (x_j[d0], x_j[d1]) f16x2, static-indexed
      #pragma unroll
      for (int j = 0; j < FN; j++) xp[j] = *(const unsigned int*)&xh[j * XS + 2 * lane];
      xp[33] = 0u; xp[34] = 0u; xp[35] = 0u;                 // zero pads: j-loop reads up to xp[35]

      float a0 = 0.f, a1 = 0.f;
      #pragma unroll
      for (int i = 0; i < 32; i++) {
        if ((i & 3) != wave) continue;                       // wave-uniform branch
        const int L   = 32 - i;
        const int n4  = (L + 3) >> 2;
        h2 ti2 = (h2)0.0f;
        #pragma unroll
        for (int t = 0; t < 8; t++) {
          if (t >= n4) break;
          u32x4 a4 = *(const u32x4*)&attn_h2[i * AS + 4 * t];  // broadcast, pads are 0
          ti2 += ash2(a4.x) * ash2(xp[i + 1 + 4 * t + 0]);     // v_pk_fma_f16
          ti2 += ash2(a4.y) * ash2(xp[i + 1 + 4 * t + 1]);
          ti2 += ash2(a4.z) * ash2(xp[i + 1 + 4 * t + 2]);
          ti2 += ash2(a4.w) * ash2(xp[i + 1 + 4 * t + 3]);
        }
        h2 xi = ash2(xp[i]);
        a0 = fmaf((float)xi[0], (float)ti2[0], a0);          // per-row combine in f32
        a1 = fmaf((float)xi[1], (float)ti2[1], a1);
      }
      *(f32x2*)&part[wave * 128 + 2 * lane] = (f32x2){a0, a1};
    }
    __syncthreads();                                         // (E)
    if (tid < DN) {
      float tot = (part[tid] + part[128 + tid]) + (part[256 + tid] + part[384 + tid]);
      out[(size_t)b * (AN + DN) + AN + tid] = tot * (100.0f / Z);
    } else {
      const int a = tid - 128;
      out[(size_t)b * (AN + DN) + a] = gnn[(size_t)b * AN + a];
    }
  }
}

extern "C" void kernel_launch(void* const* d_in, const int* in_sizes, int n_in,
                              void* d_out, int out_size, void* d_ws, size_t ws_size,
                              hipStream_t stream) {
  (void)n_in; (void)out_size; (void)d_ws; (void)ws_size;
  const float* gnn  = (const float*)d_in[0];
  const float* x    = (const float*)d_in[1];
  const float* W    = (const float*)d_in[2];
  const float* bias = (const float*)d_in[3];
  float* out = (float*)d_out;
  const int Bn = in_sizes[0] / AN;   // 1024
  afm_kernel<<<dim3(Bn / 2), dim3(256), 0, stream>>>(gnn, x, W, bias, out);
}

// Round 7
// 110.064 us; speedup vs baseline: 1.1034x; 1.1034x over previous
//
#include <hip/hip_runtime.h>

// Problem constants: B=1024, F=33, D=128, A=128, P=F*(F-1)/2=528
#define FN 33
#define DN 128
#define AN 128
#define PN 528
#define MTN 33     // P / 16 M-tiles, exact
#define XS 136     // fp16 row stride for xh in LDS (272 B, 16B-aligned, non-pow2)
#define AS 36      // u32 row stride for attn_h2 (144 B, 16B-aligned)

typedef __attribute__((ext_vector_type(8))) _Float16 half8;
typedef __attribute__((ext_vector_type(2))) _Float16 h2;
typedef __attribute__((ext_vector_type(4))) float f32x4;
typedef __attribute__((ext_vector_type(2))) float f32x2;
typedef __attribute__((ext_vector_type(4))) unsigned int u32x4;

__device__ __forceinline__ unsigned int pkrtz(float a, float b) {
  return __builtin_bit_cast(unsigned int, __builtin_amdgcn_cvt_pkrtz(a, b));
}
__device__ __forceinline__ h2 ash2(unsigned int u) { return __builtin_bit_cast(h2, u); }

// sum over the 16-lane DPP row via row_ror rotations (VALU pipe, no LDS)
__device__ __forceinline__ float row_sum16(float v) {
  v += __builtin_bit_cast(float, __builtin_amdgcn_update_dpp(0, __builtin_bit_cast(int, v), 0x128, 0xF, 0xF, false));
  v += __builtin_bit_cast(float, __builtin_amdgcn_update_dpp(0, __builtin_bit_cast(int, v), 0x124, 0xF, 0xF, false));
  v += __builtin_bit_cast(float, __builtin_amdgcn_update_dpp(0, __builtin_bit_cast(int, v), 0x122, 0xF, 0xF, false));
  v += __builtin_bit_cast(float, __builtin_amdgcn_update_dpp(0, __builtin_bit_cast(int, v), 0x121, 0xF, 0xF, false));
  return v;
}

// Block = 128 threads (2 waves), one batch row per block. Small barrier domain:
// 4 independent blocks/CU drift out of phase -> cross-block MFMA/VALU overlap.
__global__ __launch_bounds__(128, 2)
void afm_kernel(const float* __restrict__ gnn, const float* __restrict__ xg,
                const float* __restrict__ Wg,  const float* __restrict__ bg,
                float* __restrict__ out)
{
  __shared__ __align__(16) _Float16 xh[FN * XS];          // x[b] fp16, [i][d]  (8976 B)
  __shared__ __align__(16) unsigned int attn_h2[FN * AS]; // exp, dup f16x2     (4752 B)
  __shared__ __align__(16) float scores_s[PN];            // (2112 B)
  __shared__ __align__(16) float part[256];               // epilogue partials  (1024 B)
  __shared__ unsigned short rowcol[PN];                   // i | (j<<8)         (1056 B)
  __shared__ float red[4];

  const int tid  = threadIdx.x;     // 0..127
  const int b    = blockIdx.x;
  const int wave = tid >> 6;        // 0..1
  const int lane = tid & 63;
  const int q    = lane >> 4;       // quad 0..3
  const int u    = lane & 15;

  // ---------------- staging ----------------
  for (int p = tid; p < PN; p += 128) {
    int i = 0, rem = p;
    while (rem >= FN - 1 - i) { rem -= FN - 1 - i; i++; }
    rowcol[p] = (unsigned short)(i | ((i + 1 + rem) << 8));
  }
  const f32x4* xg4 = (const f32x4*)(xg + (size_t)b * FN * DN);
  for (int idx = tid; idx < (FN * DN) / 4; idx += 128) {   // 1056 float4
    f32x4 v = xg4[idx];
    int i  = idx >> 5;
    int d0 = (idx & 31) << 2;
    *(uint2*)&xh[i * XS + d0] = make_uint2(pkrtz(v.x, v.y), pkrtz(v.z, v.w));
  }
  for (int idx = tid; idx < FN * AS; idx += 128) attn_h2[idx] = 0u;

  // B-fragments from global W (L2-resident), pinned; die before the epilogue.
  // Bf[n][kk]: lane holds W[a = n*16+u][k = kk*32 + q*8 .. +7]
  half8 Bf[8][4];
  #pragma unroll
  for (int n = 0; n < 8; n++) {
    const float* wrow = Wg + (size_t)(n * 16 + u) * DN + q * 8;
    #pragma unroll
    for (int kk = 0; kk < 4; kk++) {
      f32x4 w0 = *(const f32x4*)(wrow + kk * 32);
      f32x4 w1 = *(const f32x4*)(wrow + kk * 32 + 4);
      union { half8 h; unsigned int w[4]; } t;
      t.w[0] = pkrtz(w0.x, w0.y);
      t.w[1] = pkrtz(w0.z, w0.w);
      t.w[2] = pkrtz(w1.x, w1.y);
      t.w[3] = pkrtz(w1.z, w1.w);
      Bf[n][kk] = t.h;
      asm volatile("" : "+v"(Bf[n][kk]));   // pin: forbid remat
    }
  }
  float barr[8], garr[8];
  #pragma unroll
  for (int n = 0; n < 8; n++) {
    barr[n] = bg[n * 16 + u];
    garr[n] = gnn[(size_t)b * AN + n * 16 + u];
  }
  __syncthreads();                                         // (A)

  // ---- fm matmul + score: fp16 MFMA, m-split over 2 waves, software-pipelined ----
  {
    int mt = wave;
    unsigned int rc = rowcol[mt * 16 + u];
    int r = rc & 255, c = rc >> 8;
    half8 xr[4], xc[4];
    #pragma unroll
    for (int kk = 0; kk < 4; kk++) {
      xr[kk] = *(const half8*)&xh[r * XS + kk * 32 + q * 8];
      xc[kk] = *(const half8*)&xh[c * XS + kk * 32 + q * 8];
    }
    for (;;) {
      half8 Af[4];
      #pragma unroll
      for (int kk = 0; kk < 4; kk++) Af[kk] = xr[kk] * xc[kk];   // v_pk_mul_f16

      const int nmt = mt + 2;
      if (nmt < MTN) {                                    // prefetch next tile's A rows
        rc = rowcol[nmt * 16 + u];
        r = rc & 255; c = rc >> 8;
        #pragma unroll
        for (int kk = 0; kk < 4; kk++) {
          xr[kk] = *(const half8*)&xh[r * XS + kk * 32 + q * 8];
          xc[kk] = *(const half8*)&xh[c * XS + kk * 32 + q * 8];
        }
      }

      float sc[4] = {0.f, 0.f, 0.f, 0.f};
      #pragma unroll
      for (int g = 0; g < 2; g++) {                       // n in groups of 4
        f32x4 acc[4];
        #pragma unroll
        for (int nn = 0; nn < 4; nn++) {
          float bv = barr[g * 4 + nn];                    // bias folded into acc init
          acc[nn] = (f32x4){bv, bv, bv, bv};
        }
        #pragma unroll
        for (int kk = 0; kk < 4; kk++)
          #pragma unroll
          for (int nn = 0; nn < 4; nn++)
            acc[nn] = __builtin_amdgcn_mfma_f32_16x16x32_f16(Af[kk], Bf[g * 4 + nn][kk], acc[nn], 0, 0, 0);
        #pragma unroll
        for (int nn = 0; nn < 4; nn++)
          #pragma unroll
          for (int rr = 0; rr < 4; rr++) {
            float fmv = fmaxf(acc[nn][rr], 0.f);          // relu (bias already in)
            sc[rr] = fmaf(fmv, garr[g * 4 + nn], sc[rr]);
          }
      }
      #pragma unroll
      for (int rr = 0; rr < 4; rr++) sc[rr] = row_sum16(sc[rr]);
      if (u == 0)
        *(f32x4*)&scores_s[mt * 16 + q * 4] = (f32x4){sc[0], sc[1], sc[2], sc[3]};

      if (nmt >= MTN) break;
      mt = nmt;
    }
  }
  __syncthreads();                                         // (B)

  // ---------------- softmax over 528 scores, 128 threads ----------------
  float s0 = scores_s[tid];
  float s1 = scores_s[tid + 128];
  float s2 = scores_s[tid + 256];
  float s3 = scores_s[tid + 384];
  float s4 = (tid < 16) ? scores_s[tid + 512] : -3.4e38f;
  float m = fmaxf(fmaxf(fmaxf(s0, s1), fmaxf(s2, s3)), s4);
  #pragma unroll
  for (int off = 32; off >= 1; off >>= 1) m = fmaxf(m, __shfl_xor(m, off, 64));
  if (lane == 0) red[wave] = m;
  __syncthreads();                                         // (C)
  const float smax = fmaxf(red[0], red[1]);

  float e0 = __expf(s0 - smax);
  float e1 = __expf(s1 - smax);
  float e2 = __expf(s2 - smax);
  float e3 = __expf(s3 - smax);
  float e4 = (tid < 16) ? __expf(s4 - smax) : 0.f;
  {
    unsigned int rc = rowcol[tid];
    attn_h2[(rc & 255) * AS + ((rc >> 8) - (rc & 255) - 1)] = pkrtz(e0, e0);
    rc = rowcol[tid + 128];
    attn_h2[(rc & 255) * AS + ((rc >> 8) - (rc & 255) - 1)] = pkrtz(e1, e1);
    rc = rowcol[tid + 256];
    attn_h2[(rc & 255) * AS + ((rc >> 8) - (rc & 255) - 1)] = pkrtz(e2, e2);
    rc = rowcol[tid + 384];
    attn_h2[(rc & 255) * AS + ((rc >> 8) - (rc & 255) - 1)] = pkrtz(e3, e3);
    if (tid < 16) {
      rc = rowcol[tid + 512];
      attn_h2[(rc & 255) * AS + ((rc >> 8) - (rc & 255) - 1)] = pkrtz(e4, e4);
    }
  }
  float lsum = (e0 + e1) + (e2 + e3) + e4;
  #pragma unroll
  for (int off = 32; off >= 1; off >>= 1) lsum += __shfl_xor(lsum, off, 64);
  if (lane == 0) red[2 + wave] = lsum;
  __syncthreads();                                         // (D)
  const float Z = red[2] + red[3];

  // ---- epilogue: out_d = sum_i x_i[d]*(sum_j attn_ij x_j[d]); lane owns d=2l,2l+1;
  //      wave owns rows i == wave (mod 2) ----
  {
    unsigned int xp[36];                                   // (x_j[d0], x_j[d1]) f16x2
    #pragma unroll
    for (int j = 0; j < FN; j++) xp[j] = *(const unsigned int*)&xh[j * XS + 2 * lane];
    xp[33] = 0u; xp[34] = 0u; xp[35] = 0u;                 // zero pads (j-loop reads to xp[35])

    float a0 = 0.f, a1 = 0.f;
    #pragma unroll
    for (int i = 0; i < 32; i++) {
      if ((i & 1) != wave) continue;                       // wave-uniform branch
      const int L  = 32 - i;
      const int n4 = (L + 3) >> 2;
      h2 ti2 = (h2)0.0f;
      #pragma unroll
      for (int t = 0; t < 8; t++) {
        if (t >= n4) break;
        u32x4 a4 = *(const u32x4*)&attn_h2[i * AS + 4 * t];  // broadcast, pads are 0
        ti2 += ash2(a4.x) * ash2(xp[i + 1 + 4 * t + 0]);     // v_pk_fma_f16
        ti2 += ash2(a4.y) * ash2(xp[i + 1 + 4 * t + 1]);
        ti2 += ash2(a4.z) * ash2(xp[i + 1 + 4 * t + 2]);
        ti2 += ash2(a4.w) * ash2(xp[i + 1 + 4 * t + 3]);
      }
      h2 xi = ash2(xp[i]);
      a0 = fmaf((float)xi[0], (float)ti2[0], a0);          // per-row combine in f32
      a1 = fmaf((float)xi[1], (float)ti2[1], a1);
    }
    *(f32x2*)&part[wave * 128 + 2 * lane] = (f32x2){a0, a1};
  }
  __syncthreads();                                         // (E)
  {
    out[(size_t)b * (AN + DN) + tid] = gnn[(size_t)b * AN + tid];
    float tot = part[tid] + part[128 + tid];
    out[(size_t)b * (AN + DN) + AN + tid] = tot * (100.0f / Z);
  }
}

extern "C" void kernel_launch(void* const* d_in, const int* in_sizes, int n_in,
                              void* d_out, int out_size, void* d_ws, size_t ws_size,
                              hipStream_t stream) {
  (void)n_in; (void)out_size; (void)d_ws; (void)ws_size;
  const float* gnn  = (const float*)d_in[0];
  const float* x    = (const float*)d_in[1];
  const float* W    = (const float*)d_in[2];
  const float* bias = (const float*)d_in[3];
  float* out = (float*)d_out;
  const int Bn = in_sizes[0] / AN;   // 1024
  afm_kernel<<<dim3(Bn), dim3(128), 0, stream>>>(gnn, x, W, bias, out);
}

// Round 8
// 109.596 us; speedup vs baseline: 1.1081x; 1.0043x over previous
//
#include <hip/hip_runtime.h>

// Problem constants: B=1024, F=33, D=128, A=128, P=F*(F-1)/2=528
#define FN 33
#define DN 128
#define AN 128
#define PN 528
#define MTN 33     // P / 16 M-tiles, exact
#define XS 136     // fp16 row stride for xh in LDS (272 B, 16B-aligned, non-pow2)
#define AS 36      // u32 row stride for attn_h2 (144 B, 16B-aligned)
#define SS 544     // float stride of one scores2 plane (16B-aligned)

typedef __attribute__((ext_vector_type(8))) _Float16 half8;
typedef __attribute__((ext_vector_type(2))) _Float16 h2;
typedef __attribute__((ext_vector_type(4))) float f32x4;
typedef __attribute__((ext_vector_type(2))) float f32x2;
typedef __attribute__((ext_vector_type(4))) unsigned int u32x4;

__device__ __forceinline__ unsigned int pkrtz(float a, float b) {
  return __builtin_bit_cast(unsigned int, __builtin_amdgcn_cvt_pkrtz(a, b));
}
__device__ __forceinline__ h2 ash2(unsigned int u) { return __builtin_bit_cast(h2, u); }

// sum over the 16-lane DPP row via row_ror rotations (VALU pipe, no LDS)
__device__ __forceinline__ float row_sum16(float v) {
  v += __builtin_bit_cast(float, __builtin_amdgcn_update_dpp(0, __builtin_bit_cast(int, v), 0x128, 0xF, 0xF, false));
  v += __builtin_bit_cast(float, __builtin_amdgcn_update_dpp(0, __builtin_bit_cast(int, v), 0x124, 0xF, 0xF, false));
  v += __builtin_bit_cast(float, __builtin_amdgcn_update_dpp(0, __builtin_bit_cast(int, v), 0x122, 0xF, 0xF, false));
  v += __builtin_bit_cast(float, __builtin_amdgcn_update_dpp(0, __builtin_bit_cast(int, v), 0x121, 0xF, 0xF, false));
  return v;
}

// One block = one batch row. 4 waves = (m-half, n-half) grid over the fm matmul.
// Bf is 64 regs/wave (half of W) -> total ~160 regs/wave -> 3 waves/SIMD.
__global__ __launch_bounds__(256, 3)
void afm_kernel(const float* __restrict__ gnn, const float* __restrict__ xg,
                const float* __restrict__ Wg,  const float* __restrict__ bg,
                float* __restrict__ out)
{
  __shared__ __align__(16) _Float16 xh[FN * XS];          // x[b] fp16 [i][d]    (8976 B)
  __shared__ __align__(16) unsigned int attn_h2[FN * AS]; // exp, dup f16x2      (4752 B)
  __shared__ __align__(16) float scores2[2 * SS];         // per-n-half partials (4352 B)
  __shared__ __align__(16) float part[512];               // epilogue partials   (2048 B)
  __shared__ unsigned short rowcol[PN];                   // i | (j<<8)          (1056 B)

  const int tid  = threadIdx.x;     // 0..255
  const int b    = blockIdx.x;
  const int wave = tid >> 6;        // 0..3
  const int lane = tid & 63;
  const int q    = lane >> 4;       // quad 0..3
  const int u    = lane & 15;
  const int mh   = wave >> 1;       // m-half: tiles mt == mh (mod 2)
  const int nh   = wave & 1;        // n-half: a in [nh*64, nh*64+64)

  // ---------------- staging ----------------
  for (int p = tid; p < PN; p += 256) {
    int i = 0, rem = p;
    while (rem >= FN - 1 - i) { rem -= FN - 1 - i; i++; }
    rowcol[p] = (unsigned short)(i | ((i + 1 + rem) << 8));
  }
  const f32x4* xg4 = (const f32x4*)(xg + (size_t)b * FN * DN);
  for (int idx = tid; idx < (FN * DN) / 4; idx += 256) {   // 1056 float4
    f32x4 v = xg4[idx];
    int i  = idx >> 5;
    int d0 = (idx & 31) << 2;
    *(uint2*)&xh[i * XS + d0] = make_uint2(pkrtz(v.x, v.y), pkrtz(v.z, v.w));
  }
  for (int idx = tid; idx < FN * AS; idx += 256) attn_h2[idx] = 0u;

  // B-fragments for this wave's n-half (a = (nh*4+nn)*16+u), from global W, pinned.
  half8 Bf[4][4];
  #pragma unroll
  for (int nn = 0; nn < 4; nn++) {
    const float* wrow = Wg + (size_t)((nh * 4 + nn) * 16 + u) * DN + q * 8;
    #pragma unroll
    for (int kk = 0; kk < 4; kk++) {
      f32x4 w0 = *(const f32x4*)(wrow + kk * 32);
      f32x4 w1 = *(const f32x4*)(wrow + kk * 32 + 4);
      union { half8 h; unsigned int w[4]; } t;
      t.w[0] = pkrtz(w0.x, w0.y);
      t.w[1] = pkrtz(w0.z, w0.w);
      t.w[2] = pkrtz(w1.x, w1.y);
      t.w[3] = pkrtz(w1.z, w1.w);
      Bf[nn][kk] = t.h;
      asm volatile("" : "+v"(Bf[nn][kk]));   // pin: forbid remat
    }
  }
  float garr[4];
  f32x4 bias_acc[4];     // bias pre-splatted as MFMA C operand (kills acc-init movs)
  #pragma unroll
  for (int nn = 0; nn < 4; nn++) {
    const int a = (nh * 4 + nn) * 16 + u;
    garr[nn] = gnn[(size_t)b * AN + a];
    float bv = bg[a];
    bias_acc[nn] = (f32x4){bv, bv, bv, bv};
    asm volatile("" : "+v"(garr[nn]), "+v"(bias_acc[nn]));
  }
  __syncthreads();                                         // (A)

  // ---- fm matmul + score partials: fp16 MFMA; wave does tiles mt==mh(2), n-half nh ----
  {
    int mt = mh;
    unsigned int rc = rowcol[mt * 16 + u];
    int r = rc & 255, c = rc >> 8;
    half8 xr[4], xc[4];
    #pragma unroll
    for (int kk = 0; kk < 4; kk++) {
      xr[kk] = *(const half8*)&xh[r * XS + kk * 32 + q * 8];
      xc[kk] = *(const half8*)&xh[c * XS + kk * 32 + q * 8];
    }
    for (;;) {
      f32x4 acc[4];
      #pragma unroll
      for (int kk = 0; kk < 4; kk++) {
        half8 Af = xr[kk] * xc[kk];                       // v_pk_mul_f16 x4
        #pragma unroll
        for (int nn = 0; nn < 4; nn++)
          acc[nn] = __builtin_amdgcn_mfma_f32_16x16x32_f16(
              Af, Bf[nn][kk], kk == 0 ? bias_acc[nn] : acc[nn], 0, 0, 0);
      }

      const int nmt = mt + 2;
      if (nmt < MTN) {                                    // prefetch next tile's A rows
        rc = rowcol[nmt * 16 + u];
        r = rc & 255; c = rc >> 8;
        #pragma unroll
        for (int kk = 0; kk < 4; kk++) {
          xr[kk] = *(const half8*)&xh[r * XS + kk * 32 + q * 8];
          xc[kk] = *(const half8*)&xh[c * XS + kk * 32 + q * 8];
        }
      }

      float sc[4] = {0.f, 0.f, 0.f, 0.f};
      #pragma unroll
      for (int nn = 0; nn < 4; nn++)
        #pragma unroll
        for (int rr = 0; rr < 4; rr++) {
          float fmv = fmaxf(acc[nn][rr], 0.f);            // relu (bias via MFMA C)
          sc[rr] = fmaf(fmv, garr[nn], sc[rr]);
        }
      #pragma unroll
      for (int rr = 0; rr < 4; rr++) sc[rr] = row_sum16(sc[rr]);
      if (u == 0)
        *(f32x4*)&scores2[nh * SS + mt * 16 + q * 4] = (f32x4){sc[0], sc[1], sc[2], sc[3]};

      if (nmt >= MTN) break;
      mt = nmt;
    }
  }
  __syncthreads();                                         // (B)

  // ---- softmax: each wave redundantly computes smax/Z from both score planes ----
  float s[9], e[9];
  #pragma unroll
  for (int t = 0; t < 8; t++)
    s[t] = scores2[t * 64 + lane] + scores2[SS + t * 64 + lane];
  s[8] = (lane < 16) ? (scores2[512 + lane] + scores2[SS + 512 + lane]) : -3.4e38f;
  float m = s[0];
  #pragma unroll
  for (int t = 1; t < 9; t++) m = fmaxf(m, s[t]);
  #pragma unroll
  for (int off = 32; off >= 1; off >>= 1) m = fmaxf(m, __shfl_xor(m, off, 64));
  float lsum = 0.f;
  #pragma unroll
  for (int t = 0; t < 9; t++) {
    e[t] = (t == 8 && lane >= 16) ? 0.f : __expf(s[t] - m);
    lsum += e[t];
  }
  #pragma unroll
  for (int off = 32; off >= 1; off >>= 1) lsum += __shfl_xor(lsum, off, 64);
  const float Z = lsum;   // identical in all waves (same inputs, same op order)

  // attn scatter: wave w owns t = 2w, 2w+1; wave 3 also t = 8
  #pragma unroll
  for (int t = 0; t < 9; t++) {
    bool mine = (t < 8) ? ((t >> 1) == wave) : (wave == 3 && lane < 16);
    if (mine) {
      unsigned int rc = rowcol[t * 64 + lane];
      attn_h2[(rc & 255) * AS + ((rc >> 8) - (rc & 255) - 1)] = pkrtz(e[t], e[t]);
    }
  }
  __syncthreads();                                         // (C)

  // ---- epilogue: out_d = sum_i x_i[d]*(sum_j attn_ij x_j[d]); lane owns d=2l,2l+1;
  //      wave owns rows i == wave (mod 4) ----
  {
    unsigned int xp[36];                                   // (x_j[d0], x_j[d1]) f16x2
    #pragma unroll
    for (int j = 0; j < FN; j++) xp[j] = *(const unsigned int*)&xh[j * XS + 2 * lane];
    xp[33] = 0u; xp[34] = 0u; xp[35] = 0u;                 // zero pads (j-loop reads to xp[35])

    float a0 = 0.f, a1 = 0.f;
    #pragma unroll
    for (int i = 0; i < 32; i++) {
      if ((i & 3) != wave) continue;                       // wave-uniform branch
      const int L  = 32 - i;
      const int n4 = (L + 3) >> 2;
      h2 ti2 = (h2)0.0f;
      #pragma unroll
      for (int t = 0; t < 8; t++) {
        if (t >= n4) break;
        u32x4 a4 = *(const u32x4*)&attn_h2[i * AS + 4 * t];  // broadcast, pads are 0
        ti2 += ash2(a4.x) * ash2(xp[i + 1 + 4 * t + 0]);     // v_pk_fma_f16
        ti2 += ash2(a4.y) * ash2(xp[i + 1 + 4 * t + 1]);
        ti2 += ash2(a4.z) * ash2(xp[i + 1 + 4 * t + 2]);
        ti2 += ash2(a4.w) * ash2(xp[i + 1 + 4 * t + 3]);
      }
      h2 xi = ash2(xp[i]);
      a0 = fmaf((float)xi[0], (float)ti2[0], a0);          // per-row combine in f32
      a1 = fmaf((float)xi[1], (float)ti2[1], a1);
    }
    *(f32x2*)&part[wave * 128 + 2 * lane] = (f32x2){a0, a1};
  }
  __syncthreads();                                         // (D)
  if (tid < DN) {
    float tot = (part[tid] + part[128 + tid]) + (part[256 + tid] + part[384 + tid]);
    out[(size_t)b * (AN + DN) + AN + tid] = tot * (100.0f / Z);
  } else {
    const int a = tid - 128;
    out[(size_t)b * (AN + DN) + a] = gnn[(size_t)b * AN + a];
  }
}

extern "C" void kernel_launch(void* const* d_in, const int* in_sizes, int n_in,
                              void* d_out, int out_size, void* d_ws, size_t ws_size,
                              hipStream_t stream) {
  (void)n_in; (void)out_size; (void)d_ws; (void)ws_size;
  const float* gnn  = (const float*)d_in[0];
  const float* x    = (const float*)d_in[1];
  const float* W    = (const float*)d_in[2];
  const float* bias = (const float*)d_in[3];
  float* out = (float*)d_out;
  const int Bn = in_sizes[0] / AN;   // 1024
  afm_kernel<<<dim3(Bn), dim3(256), 0, stream>>>(gnn, x, W, bias, out);
}